// Round 13
// baseline (502.297 us; speedup 1.0000x reference)
//
#include <hip/hip_runtime.h>

#define NN 500
#define BB 8
#define FIN 8
#define TT 12
#define HH 16
#define EE 8000
#define HG 4000          // N*HID
#define IG 8000          // N*H3
#define G3 12000         // 3*HG
#define MM 96            // T*B
#define NSL 8            // k-slices for gh split-K

typedef __attribute__((ext_vector_type(8))) _Float16 half8;
typedef __attribute__((ext_vector_type(4))) _Float16 half4v;
typedef __attribute__((ext_vector_type(4))) float f32x4;

// -------------------------------- graph prep (block 0) + input transpose (rest)
// transpose covers TT*NN*BB*FIN = 384000 elements -> 750 blocks x 512; +1 prep block.
__global__ __launch_bounds__(512) void k_prep_tr(const int* __restrict__ src,
                                                 const int* __restrict__ dst,
                                                 float* __restrict__ n_out,
                                                 float* __restrict__ n_in,
                                                 int* __restrict__ row_ptr,
                                                 int* __restrict__ edge_src,
                                                 const float* __restrict__ xin,
                                                 float* __restrict__ x0) {
  int tid = threadIdx.x;
  if (blockIdx.x != 0) {
    int idx = (blockIdx.x - 1) * 512 + tid;      // over 384000 exactly
    if (idx < TT * NN * BB * FIN) {
      int f = idx % FIN;
      int b = (idx / FIN) % BB;
      int n = (idx / (FIN * BB)) % NN;
      int t = idx / (FIN * BB * NN);
      x0[idx] = xin[((n * BB + b) * FIN + f) * TT + t];
    }
    return;
  }
  __shared__ int s_dout[NN];
  __shared__ int s_din[NN];
  __shared__ int s_off[NN + 1];
  for (int i = tid; i < NN; i += 512) { s_dout[i] = 0; s_din[i] = 0; }
  __syncthreads();
  for (int e = tid; e < EE; e += 512) {
    atomicAdd(&s_dout[src[e]], 1);
    atomicAdd(&s_din[dst[e]], 1);
  }
  __syncthreads();
  if (tid == 0) {
    int acc = 0;
    for (int n = 0; n < NN; ++n) { s_off[n] = acc; acc += s_din[n]; }
    s_off[NN] = acc;
  }
  __syncthreads();
  for (int i = tid; i < NN; i += 512) {
    int dv = s_dout[i]; if (dv < 1) dv = 1;
    int iv = s_din[i];  if (iv < 1) iv = 1;
    n_out[i] = rsqrtf((float)dv);
    n_in[i]  = rsqrtf((float)iv);
    row_ptr[i] = s_off[i];
  }
  if (tid == 0) row_ptr[NN] = s_off[NN];
  __syncthreads();
  for (int e = tid; e < EE; e += 512) {
    int d = dst[e];
    int pos = atomicAdd(&s_off[d], 1);
    edge_src[pos] = src[e];
  }
}

// ---------------------------------------------------------------- GCN layer
template <int FI, int FO, bool RELU, typename OT, bool OUT_SEQ>
__global__ __launch_bounds__(128) void k_gcn(const float* __restrict__ x,
                                             const float* __restrict__ W,
                                             const float* __restrict__ bias,
                                             const float* __restrict__ n_out,
                                             const float* __restrict__ n_in,
                                             const int* __restrict__ row_ptr,
                                             const int* __restrict__ edge_src,
                                             OT* __restrict__ y) {
  int bid = blockIdx.x;             // t*NN + n
  int t = bid / NN, n = bid % NN;
  __shared__ float sW[FI * FO];
  __shared__ float sB[FO];
  __shared__ float sAgg[BB * FI];
  int tid = threadIdx.x;
  for (int i = tid; i < FI * FO; i += 128) sW[i] = W[i];
  if (tid < FO) sB[tid] = bias[tid];
  int r0 = row_ptr[n], r1 = row_ptr[n + 1];
  if (tid < BB * FI) {
    int b = tid / FI, fi = tid % FI;
    float acc = 0.f;
    for (int p = r0; p < r1; ++p) {
      int s = edge_src[p];
      acc += x[((t * NN + s) * BB + b) * FI + fi] * n_out[s];
    }
    sAgg[tid] = acc * n_in[n];
  }
  __syncthreads();
  if (tid < BB * FO) {
    int b = tid / FO, fo = tid % FO;
    float v = sB[fo];
#pragma unroll
    for (int fi = 0; fi < FI; ++fi) v += sAgg[b * FI + fi] * sW[fi * FO + fo];
    if (RELU) v = fmaxf(v, 0.f);
    int oidx = OUT_SEQ ? (((t * BB + b) * NN + n) * FO + fo)
                       : (((t * NN + n) * BB + b) * FO + fo);
    y[oidx] = (OT)v;
  }
}

// ------------------------------------------------------------ gi = X @ Wih^T
// fp16 MFMA single pass.  Xh: [96][8000] fp16, Wih: [12000][8000] fp32 (cvt in-kernel).
// gip: [2][96][12000] K-split partials.  grid (375, 2), block 256 (4 waves).
__global__ __launch_bounds__(256, 3) void k_gemm_gi_mfma(const _Float16* __restrict__ Xh,
                                                         const float* __restrict__ Wih,
                                                         float* __restrict__ gip) {
  __shared__ _Float16 sXh[96 * 40];   // rows padded to 40 halves (80B stride)
  __shared__ _Float16 sWh[32 * 40];
  int tid = threadIdx.x;
  int wave = tid >> 6, lane = tid & 63;
  int jb = blockIdx.x * 32;
  int kbase = blockIdx.y * 4000;       // K_s = 4000, 125 chunks of 32

  int xrow[3], xc4[3];
  const ushort4* px[3];
#pragma unroll
  for (int i = 0; i < 3; ++i) {
    int idx = i * 256 + tid;           // 768 units = 96 rows x 8 half4
    xrow[i] = idx >> 3; xc4[i] = idx & 7;
    px[i] = (const ushort4*)(Xh + (size_t)xrow[i] * IG + kbase + xc4[i] * 4);
  }
  int wrow = tid >> 3, wc4 = tid & 7;  // 256 f4 = 32 rows x 8 f4
  const float4* pw = (const float4*)(Wih + (size_t)(jb + wrow) * IG + kbase + wc4 * 4);

  int jt = wave & 1;                    // j-tile within block
  int mh = wave >> 1;                   // m-half (48 rows)
  f32x4 acc[3] = {{0.f,0.f,0.f,0.f},{0.f,0.f,0.f,0.f},{0.f,0.f,0.f,0.f}};

  ushort4 xr[3]; float4 wr;
#pragma unroll
  for (int i = 0; i < 3; ++i) xr[i] = px[i][0];
  wr = pw[0];

  int l15 = lane & 15;
  int colh = (lane >> 4) * 8;

  for (int c = 0; c < 125; ++c) {
    __syncthreads();
#pragma unroll
    for (int i = 0; i < 3; ++i)
      *(ushort4*)&sXh[xrow[i] * 40 + xc4[i] * 4] = xr[i];
    {
      half4v h;
      h[0] = (_Float16)wr.x; h[1] = (_Float16)wr.y;
      h[2] = (_Float16)wr.z; h[3] = (_Float16)wr.w;
      *(half4v*)&sWh[wrow * 40 + wc4 * 4] = h;
    }
    __syncthreads();
    if (c < 124) {
#pragma unroll
      for (int i = 0; i < 3; ++i) xr[i] = px[i][(c + 1) * 8];
      wr = pw[(c + 1) * 8];
    }
    half8 bfrag = *(const half8*)&sWh[(jt * 16 + l15) * 40 + colh];
#pragma unroll
    for (int t = 0; t < 3; ++t) {
      half8 afrag = *(const half8*)&sXh[(mh * 48 + t * 16 + l15) * 40 + colh];
      acc[t] = __builtin_amdgcn_mfma_f32_16x16x32_f16(afrag, bfrag, acc[t], 0, 0, 0);
    }
  }

  // D: col = lane&15 (j), row m = (lane>>4)*4 + reg  [validated rounds 3-11]
  float* out = gip + (size_t)blockIdx.y * (MM * G3);
  int j = jb + jt * 16 + l15;
#pragma unroll
  for (int t = 0; t < 3; ++t) {
    int mb = mh * 48 + t * 16 + (lane >> 4) * 4;
#pragma unroll
    for (int r = 0; r < 4; ++r)
      out[(size_t)(mb + r) * G3 + j] = acc[t][r];
  }
}

// ------------------------------------------------- GRU step 0 (h=0 -> gh=0)
__global__ __launch_bounds__(256) void k_gates0(const float* __restrict__ gip,
                                                const float* __restrict__ b_ih,
                                                const float* __restrict__ b_hh,
                                                float* __restrict__ h32n,
                                                _Float16* __restrict__ h_t) {
  int idx = blockIdx.x * 256 + threadIdx.x;   // 32000 exact (125 blocks)
  int q = idx >> 3, m = idx & 7;
  const float* g0 = gip + (size_t)m * G3;                     // t=0: mg = m
  const float* g1 = gip + (size_t)MM * G3 + (size_t)m * G3;
  float ir  = b_ih[q]          + g0[q]          + g1[q];
  float iz  = b_ih[q + HG]     + g0[q + HG]     + g1[q + HG];
  float in_ = b_ih[q + 2*HG]   + g0[q + 2*HG]   + g1[q + 2*HG];
  float r = 1.f / (1.f + __expf(-(ir + b_hh[q])));
  float z = 1.f / (1.f + __expf(-(iz + b_hh[q + HG])));
  float nn = tanhf(in_ + r * b_hh[q + 2*HG]);
  float h = (1.f - z) * nn;                   // h_old = 0
  h32n[idx] = h;
  h_t[(size_t)m * HG + q] = (_Float16)h;      // transposed fp16 for MFMA B-operand
}

// slice geometry: 125 K-chunks (32 halves each) split 5x16 + 3x15
__device__ __forceinline__ int slice_base(int ks) {   // in halves
  return (ks < 5) ? ks * 512 : 2560 + (ks - 5) * 480;
}
__device__ __forceinline__ int slice_chunks(int ks) { return (ks < 5) ? 16 : 15; }

// ------------------------------------------------------------ gh = Whh @ h (MFMA)
// A = 16 W-rows direct from global; B = h_t[8][4000] fp16 (L1/L2-resident).
// grid (188, 8): 64 j per block (4 waves x 16), 8 k-slices -> 1504 blocks
// (~6/CU, 24 waves/CU) for memory-level parallelism on the L3 W-stream.
__global__ __launch_bounds__(256) void k_ghm(const _Float16* __restrict__ wh,
                                             const _Float16* __restrict__ h_t,
                                             float* __restrict__ ghp) {
  int tid = threadIdx.x;
  int wave = tid >> 6, lane = tid & 63;
  int ks = blockIdx.y;
  int kbase = slice_base(ks);
  int kn = slice_chunks(ks);
  int l15 = lane & 15;
  int ko = (lane >> 4) * 8;
  int row = blockIdx.x * 64 + wave * 16 + l15;
  int rowc = row < G3 ? row : G3 - 1;  // clamp tail (store masked below)
  const half8* __restrict__ A  = (const half8*)(wh + (size_t)rowc * HG + kbase + ko);
  const half8* __restrict__ Bp = (const half8*)(h_t + (size_t)(l15 & 7) * HG + kbase + ko);
  f32x4 acc = {0.f, 0.f, 0.f, 0.f};
#pragma unroll 4
  for (int i = 0; i < kn; ++i)
    acc = __builtin_amdgcn_mfma_f32_16x16x32_f16(A[i * 4], Bp[i * 4], acc, 0, 0, 0);
  if (l15 < 8) {
    float* outp = ghp + (size_t)ks * (BB * G3) + (size_t)l15 * G3;
    int jb = blockIdx.x * 64 + wave * 16 + (lane >> 4) * 4;
#pragma unroll
    for (int r = 0; r < 4; ++r) {
      int j = jb + r;
      if (j < G3) outp[j] = acc[r];
    }
  }
}

// ---------------- step-1 variant: reads fp32 Whh, converts, writes fp16 copy
__global__ __launch_bounds__(256) void k_ghcvtm(const float* __restrict__ Whh,
                                                _Float16* __restrict__ whh_h,
                                                const _Float16* __restrict__ h_t,
                                                float* __restrict__ ghp) {
  int tid = threadIdx.x;
  int wave = tid >> 6, lane = tid & 63;
  int ks = blockIdx.y;
  int kbase = slice_base(ks);
  int kn = slice_chunks(ks);
  int l15 = lane & 15;
  int ko = (lane >> 4) * 8;
  int row = blockIdx.x * 64 + wave * 16 + l15;
  int rowc = row < G3 ? row : G3 - 1;
  const float4* __restrict__ F = (const float4*)(Whh + (size_t)rowc * HG + kbase + ko);
  half8* __restrict__ O = (half8*)(whh_h + (size_t)rowc * HG + kbase + ko);
  const half8* __restrict__ Bp = (const half8*)(h_t + (size_t)(l15 & 7) * HG + kbase + ko);
  f32x4 acc = {0.f, 0.f, 0.f, 0.f};
#pragma unroll 2
  for (int i = 0; i < kn; ++i) {
    float4 x = F[i * 8], y = F[i * 8 + 1];
    half8 a;
    a[0] = (_Float16)x.x; a[1] = (_Float16)x.y; a[2] = (_Float16)x.z; a[3] = (_Float16)x.w;
    a[4] = (_Float16)y.x; a[5] = (_Float16)y.y; a[6] = (_Float16)y.z; a[7] = (_Float16)y.w;
    O[i * 4] = a;                      // clamped tail rows rewrite same bytes: benign
    acc = __builtin_amdgcn_mfma_f32_16x16x32_f16(a, Bp[i * 4], acc, 0, 0, 0);
  }
  if (l15 < 8) {
    float* outp = ghp + (size_t)ks * (BB * G3) + (size_t)l15 * G3;
    int jb = blockIdx.x * 64 + wave * 16 + (lane >> 4) * 4;
#pragma unroll
    for (int r = 0; r < 4; ++r) {
      int j = jb + r;
      if (j < G3) outp[j] = acc[r];
    }
  }
}

// ---------------------------------------------------------------- gates
__global__ __launch_bounds__(256) void k_gates(const float* __restrict__ gip,
                                               const float* __restrict__ ghp,
                                               const float* __restrict__ b_ih,
                                               const float* __restrict__ b_hh,
                                               const float* __restrict__ ht_old,
                                               float* __restrict__ ht_new,
                                               _Float16* __restrict__ h_t,
                                               float* __restrict__ hout, int t) {
  int idx = blockIdx.x * 256 + threadIdx.x;
  if (idx >= BB * HG) return;
  int b = idx / HG, q = idx % HG;
  int m = t * BB + b;
  const float* g0 = gip;
  const float* g1 = gip + (size_t)MM * G3;
  float ir = b_ih[q]          + g0[m * G3 + q]          + g1[m * G3 + q];
  float iz = b_ih[q + HG]     + g0[m * G3 + q + HG]     + g1[m * G3 + q + HG];
  float in_ = b_ih[q + 2*HG]  + g0[m * G3 + q + 2*HG]   + g1[m * G3 + q + 2*HG];
  float hr = b_hh[q], hz = b_hh[q + HG], hn = b_hh[q + 2*HG];
#pragma unroll
  for (int s = 0; s < NSL; ++s) {
    const float* gh = ghp + (size_t)s * (BB * G3) + b * G3;
    hr += gh[q]; hz += gh[q + HG]; hn += gh[q + 2*HG];
  }
  float r = 1.f / (1.f + __expf(-(ir + hr)));
  float z = 1.f / (1.f + __expf(-(iz + hz)));
  float nn = tanhf(in_ + r * hn);
  float ho = ht_old[q * BB + b];
  float h = (1.f - z) * nn + z * ho;
  ht_new[q * BB + b] = h;
  h_t[(size_t)b * HG + q] = (_Float16)h;
  if (hout) hout[b * HG + q] = h;
}

// ---------------------------------------------------------------- launcher
extern "C" void kernel_launch(void* const* d_in, const int* in_sizes, int n_in,
                              void* d_out, int out_size, void* d_ws, size_t ws_size,
                              hipStream_t stream) {
  const float* x_in = (const float*)d_in[0];
  const int*   src  = (const int*)d_in[1];
  const int*   dst  = (const int*)d_in[2];
  const float* W1   = (const float*)d_in[3];
  const float* b1   = (const float*)d_in[4];
  const float* W2   = (const float*)d_in[5];
  const float* b2   = (const float*)d_in[6];
  const float* W3   = (const float*)d_in[7];
  const float* b3   = (const float*)d_in[8];
  const float* Wih  = (const float*)d_in[9];
  const float* Whh  = (const float*)d_in[10];
  const float* bih  = (const float*)d_in[11];
  const float* bhh  = (const float*)d_in[12];
  float* out = (float*)d_out;

  float* W = (float*)d_ws;
  size_t off = 0;
  float* n_out = W + off; off += 512;
  float* n_in_ = W + off; off += 512;
  float* x0    = W + off; off += (size_t)TT * NN * BB * FIN;   // 384000
  float* xa    = W + off; off += (size_t)TT * NN * BB * HH;    // 768000
  float* xb    = W + off; off += (size_t)TT * NN * BB * HH;    // 768000
  _Float16* xseq = (_Float16*)(W + off); off += (size_t)MM * IG / 2;
  float* gip   = W + off; off += (size_t)2 * MM * G3;          // 2304000
  float* ghp   = W + off; off += (size_t)NSL * BB * G3;        // 768000
  float* ht0   = W + off; off += (size_t)HG * BB;
  float* ht1   = W + off; off += (size_t)HG * BB;
  _Float16* h_t = (_Float16*)(W + off); off += (size_t)HG * BB / 2;  // [8][4000] fp16
  int* row_ptr  = (int*)(W + off); off += 512;
  int* edge_src = (int*)(W + off); off += 8000;
  off = (off + 3) & ~(size_t)3;                                // 16B align
  _Float16* whh_h = (_Float16*)(W + off); off += (size_t)G3 * HG / 2 + 64;  // 96 MB
  (void)ws_size; (void)in_sizes; (void)n_in; (void)out_size;

  k_prep_tr<<<751, 512, 0, stream>>>(src, dst, n_out, n_in_, row_ptr, edge_src, x_in, x0);
  k_gcn<FIN, HH, true, float, false><<<TT * NN, 128, 0, stream>>>(x0, W1, b1, n_out, n_in_, row_ptr, edge_src, xa);
  k_gcn<HH, HH, true, float, false><<<TT * NN, 128, 0, stream>>>(xa, W2, b2, n_out, n_in_, row_ptr, edge_src, xb);
  k_gcn<HH, HH, false, _Float16, true><<<TT * NN, 128, 0, stream>>>(xb, W3, b3, n_out, n_in_, row_ptr, edge_src, xseq);
  k_gemm_gi_mfma<<<dim3(375, 2), 256, 0, stream>>>(xseq, Wih, gip);

  // t = 0: h_old = 0 -> gh = 0, skip the W_hh stream entirely
  k_gates0<<<BB * HG / 256, 256, 0, stream>>>(gip, bih, bhh, ht0, h_t);

  float* hcur = ht0;
  float* hnxt = ht1;
  // t = 1: gh fused with the one-time fp32->fp16 W_hh conversion
  k_ghcvtm<<<dim3(188, NSL), 256, 0, stream>>>(Whh, whh_h, h_t, ghp);
  k_gates<<<(BB * HG + 255) / 256, 256, 0, stream>>>(
      gip, ghp, bih, bhh, hcur, hnxt, h_t, nullptr, 1);
  { float* tmp = hcur; hcur = hnxt; hnxt = tmp; }

  for (int t = 2; t < TT; ++t) {
    k_ghm<<<dim3(188, NSL), 256, 0, stream>>>(whh_h, h_t, ghp);
    k_gates<<<(BB * HG + 255) / 256, 256, 0, stream>>>(
        gip, ghp, bih, bhh, hcur, hnxt, h_t, (t == TT - 1) ? out : nullptr, t);
    float* tmp = hcur; hcur = hnxt; hnxt = tmp;
  }
}

// Round 14
// 469.163 us; speedup vs baseline: 1.0706x; 1.0706x over previous
//
#include <hip/hip_runtime.h>

#define NN 500
#define BB 8
#define FIN 8
#define TT 12
#define HH 16
#define EE 8000
#define HG 4000          // N*HID
#define IG 8000          // N*H3
#define G3 12000         // 3*HG
#define MM 96            // T*B
#define NSL 4            // k-slices for gh split-K (4 = measured sweet spot, r11 vs r13)

typedef __attribute__((ext_vector_type(8))) _Float16 half8;
typedef __attribute__((ext_vector_type(4))) _Float16 half4v;
typedef __attribute__((ext_vector_type(4))) float f32x4;

// -------------------------------- graph prep (block 0) + input transpose (rest)
// transpose covers TT*NN*BB*FIN = 384000 elements -> 750 blocks x 512; +1 prep block.
__global__ __launch_bounds__(512) void k_prep_tr(const int* __restrict__ src,
                                                 const int* __restrict__ dst,
                                                 float* __restrict__ n_out,
                                                 float* __restrict__ n_in,
                                                 int* __restrict__ row_ptr,
                                                 int* __restrict__ edge_src,
                                                 const float* __restrict__ xin,
                                                 float* __restrict__ x0) {
  int tid = threadIdx.x;
  if (blockIdx.x != 0) {
    int idx = (blockIdx.x - 1) * 512 + tid;      // over 384000 exactly
    if (idx < TT * NN * BB * FIN) {
      int f = idx % FIN;
      int b = (idx / FIN) % BB;
      int n = (idx / (FIN * BB)) % NN;
      int t = idx / (FIN * BB * NN);
      x0[idx] = xin[((n * BB + b) * FIN + f) * TT + t];
    }
    return;
  }
  __shared__ int s_dout[NN];
  __shared__ int s_din[NN];
  __shared__ int s_off[NN + 1];
  for (int i = tid; i < NN; i += 512) { s_dout[i] = 0; s_din[i] = 0; }
  __syncthreads();
  for (int e = tid; e < EE; e += 512) {
    atomicAdd(&s_dout[src[e]], 1);
    atomicAdd(&s_din[dst[e]], 1);
  }
  __syncthreads();
  if (tid == 0) {
    int acc = 0;
    for (int n = 0; n < NN; ++n) { s_off[n] = acc; acc += s_din[n]; }
    s_off[NN] = acc;
  }
  __syncthreads();
  for (int i = tid; i < NN; i += 512) {
    int dv = s_dout[i]; if (dv < 1) dv = 1;
    int iv = s_din[i];  if (iv < 1) iv = 1;
    n_out[i] = rsqrtf((float)dv);
    n_in[i]  = rsqrtf((float)iv);
    row_ptr[i] = s_off[i];
  }
  if (tid == 0) row_ptr[NN] = s_off[NN];
  __syncthreads();
  for (int e = tid; e < EE; e += 512) {
    int d = dst[e];
    int pos = atomicAdd(&s_off[d], 1);
    edge_src[pos] = src[e];
  }
}

// ---------------------------------------------------------------- GCN layer
template <int FI, int FO, bool RELU, typename OT, bool OUT_SEQ>
__global__ __launch_bounds__(128) void k_gcn(const float* __restrict__ x,
                                             const float* __restrict__ W,
                                             const float* __restrict__ bias,
                                             const float* __restrict__ n_out,
                                             const float* __restrict__ n_in,
                                             const int* __restrict__ row_ptr,
                                             const int* __restrict__ edge_src,
                                             OT* __restrict__ y) {
  int bid = blockIdx.x;             // t*NN + n
  int t = bid / NN, n = bid % NN;
  __shared__ float sW[FI * FO];
  __shared__ float sB[FO];
  __shared__ float sAgg[BB * FI];
  int tid = threadIdx.x;
  for (int i = tid; i < FI * FO; i += 128) sW[i] = W[i];
  if (tid < FO) sB[tid] = bias[tid];
  int r0 = row_ptr[n], r1 = row_ptr[n + 1];
  if (tid < BB * FI) {
    int b = tid / FI, fi = tid % FI;
    float acc = 0.f;
    for (int p = r0; p < r1; ++p) {
      int s = edge_src[p];
      acc += x[((t * NN + s) * BB + b) * FI + fi] * n_out[s];
    }
    sAgg[tid] = acc * n_in[n];
  }
  __syncthreads();
  if (tid < BB * FO) {
    int b = tid / FO, fo = tid % FO;
    float v = sB[fo];
#pragma unroll
    for (int fi = 0; fi < FI; ++fi) v += sAgg[b * FI + fi] * sW[fi * FO + fo];
    if (RELU) v = fmaxf(v, 0.f);
    int oidx = OUT_SEQ ? (((t * BB + b) * NN + n) * FO + fo)
                       : (((t * NN + n) * BB + b) * FO + fo);
    y[oidx] = (OT)v;
  }
}

// ------------------------------------------------------------ gi = X @ Wih^T
// fp16 MFMA single pass.  Xh: [96][8000] fp16, Wih: [12000][8000] fp32 (cvt in-kernel).
// gip: [2][96][12000] K-split partials.  grid (375, 2), block 256 (4 waves).
__global__ __launch_bounds__(256, 3) void k_gemm_gi_mfma(const _Float16* __restrict__ Xh,
                                                         const float* __restrict__ Wih,
                                                         float* __restrict__ gip) {
  __shared__ _Float16 sXh[96 * 40];   // rows padded to 40 halves (80B stride)
  __shared__ _Float16 sWh[32 * 40];
  int tid = threadIdx.x;
  int wave = tid >> 6, lane = tid & 63;
  int jb = blockIdx.x * 32;
  int kbase = blockIdx.y * 4000;       // K_s = 4000, 125 chunks of 32

  int xrow[3], xc4[3];
  const ushort4* px[3];
#pragma unroll
  for (int i = 0; i < 3; ++i) {
    int idx = i * 256 + tid;           // 768 units = 96 rows x 8 half4
    xrow[i] = idx >> 3; xc4[i] = idx & 7;
    px[i] = (const ushort4*)(Xh + (size_t)xrow[i] * IG + kbase + xc4[i] * 4);
  }
  int wrow = tid >> 3, wc4 = tid & 7;  // 256 f4 = 32 rows x 8 f4
  const float4* pw = (const float4*)(Wih + (size_t)(jb + wrow) * IG + kbase + wc4 * 4);

  int jt = wave & 1;                    // j-tile within block
  int mh = wave >> 1;                   // m-half (48 rows)
  f32x4 acc[3] = {{0.f,0.f,0.f,0.f},{0.f,0.f,0.f,0.f},{0.f,0.f,0.f,0.f}};

  ushort4 xr[3]; float4 wr;
#pragma unroll
  for (int i = 0; i < 3; ++i) xr[i] = px[i][0];
  wr = pw[0];

  int l15 = lane & 15;
  int colh = (lane >> 4) * 8;

  for (int c = 0; c < 125; ++c) {
    __syncthreads();
#pragma unroll
    for (int i = 0; i < 3; ++i)
      *(ushort4*)&sXh[xrow[i] * 40 + xc4[i] * 4] = xr[i];
    {
      half4v h;
      h[0] = (_Float16)wr.x; h[1] = (_Float16)wr.y;
      h[2] = (_Float16)wr.z; h[3] = (_Float16)wr.w;
      *(half4v*)&sWh[wrow * 40 + wc4 * 4] = h;
    }
    __syncthreads();
    if (c < 124) {
#pragma unroll
      for (int i = 0; i < 3; ++i) xr[i] = px[i][(c + 1) * 8];
      wr = pw[(c + 1) * 8];
    }
    half8 bfrag = *(const half8*)&sWh[(jt * 16 + l15) * 40 + colh];
#pragma unroll
    for (int t = 0; t < 3; ++t) {
      half8 afrag = *(const half8*)&sXh[(mh * 48 + t * 16 + l15) * 40 + colh];
      acc[t] = __builtin_amdgcn_mfma_f32_16x16x32_f16(afrag, bfrag, acc[t], 0, 0, 0);
    }
  }

  // D: col = lane&15 (j), row m = (lane>>4)*4 + reg  [validated rounds 3-13]
  float* out = gip + (size_t)blockIdx.y * (MM * G3);
  int j = jb + jt * 16 + l15;
#pragma unroll
  for (int t = 0; t < 3; ++t) {
    int mb = mh * 48 + t * 16 + (lane >> 4) * 4;
#pragma unroll
    for (int r = 0; r < 4; ++r)
      out[(size_t)(mb + r) * G3 + j] = acc[t][r];
  }
}

// ------------------------------------------------- GRU step 0 (h=0 -> gh=0)
__global__ __launch_bounds__(256) void k_gates0(const float* __restrict__ gip,
                                                const float* __restrict__ b_ih,
                                                const float* __restrict__ b_hh,
                                                float* __restrict__ h32n,
                                                _Float16* __restrict__ h_t) {
  int idx = blockIdx.x * 256 + threadIdx.x;   // 32000 exact (125 blocks)
  int q = idx >> 3, m = idx & 7;
  const float* g0 = gip + (size_t)m * G3;                     // t=0: mg = m
  const float* g1 = gip + (size_t)MM * G3 + (size_t)m * G3;
  float ir  = b_ih[q]          + g0[q]          + g1[q];
  float iz  = b_ih[q + HG]     + g0[q + HG]     + g1[q + HG];
  float in_ = b_ih[q + 2*HG]   + g0[q + 2*HG]   + g1[q + 2*HG];
  float r = 1.f / (1.f + __expf(-(ir + b_hh[q])));
  float z = 1.f / (1.f + __expf(-(iz + b_hh[q + HG])));
  float nn = tanhf(in_ + r * b_hh[q + 2*HG]);
  float h = (1.f - z) * nn;                   // h_old = 0
  h32n[idx] = h;
  h_t[(size_t)m * HG + q] = (_Float16)h;      // transposed fp16 for MFMA B-operand
}

// ------------------------------------------------------------ gh = Whh @ h (MFMA)
// A = 16 W-rows direct from global; B = h_t[8][4000] fp16 (L1/L2-resident).
// grid (188, 4): 64 j per block (4 waves x 16), k-slices {1024,1024,1024,928}.
// 752 blocks (~3/CU) measured optimal (r11=471 vs r13 8-way=502).
__global__ __launch_bounds__(256) void k_ghm(const _Float16* __restrict__ wh,
                                             const _Float16* __restrict__ h_t,
                                             float* __restrict__ ghp) {
  int tid = threadIdx.x;
  int wave = tid >> 6, lane = tid & 63;
  int ks = blockIdx.y;
  int kbase = ks * 1024;
  int kn = (ks == 3) ? 29 : 32;        // 928 = 29*32
  int l15 = lane & 15;
  int ko = (lane >> 4) * 8;
  int row = blockIdx.x * 64 + wave * 16 + l15;
  int rowc = row < G3 ? row : G3 - 1;  // clamp tail (store masked below)
  const half8* __restrict__ A  = (const half8*)(wh + (size_t)rowc * HG + kbase + ko);
  const half8* __restrict__ Bp = (const half8*)(h_t + (size_t)(l15 & 7) * HG + kbase + ko);
  f32x4 acc = {0.f, 0.f, 0.f, 0.f};
#pragma unroll 4
  for (int i = 0; i < kn; ++i)
    acc = __builtin_amdgcn_mfma_f32_16x16x32_f16(A[i * 4], Bp[i * 4], acc, 0, 0, 0);
  if (l15 < 8) {
    float* outp = ghp + (size_t)ks * (BB * G3) + (size_t)l15 * G3;
    int jb = blockIdx.x * 64 + wave * 16 + (lane >> 4) * 4;
#pragma unroll
    for (int r = 0; r < 4; ++r) {
      int j = jb + r;
      if (j < G3) outp[j] = acc[r];
    }
  }
}

// ---------------- step-1 variant: reads fp32 Whh, converts, writes fp16 copy
__global__ __launch_bounds__(256) void k_ghcvtm(const float* __restrict__ Whh,
                                                _Float16* __restrict__ whh_h,
                                                const _Float16* __restrict__ h_t,
                                                float* __restrict__ ghp) {
  int tid = threadIdx.x;
  int wave = tid >> 6, lane = tid & 63;
  int ks = blockIdx.y;
  int kbase = ks * 1024;
  int kn = (ks == 3) ? 29 : 32;
  int l15 = lane & 15;
  int ko = (lane >> 4) * 8;
  int row = blockIdx.x * 64 + wave * 16 + l15;
  int rowc = row < G3 ? row : G3 - 1;
  const float4* __restrict__ F = (const float4*)(Whh + (size_t)rowc * HG + kbase + ko);
  half8* __restrict__ O = (half8*)(whh_h + (size_t)rowc * HG + kbase + ko);
  const half8* __restrict__ Bp = (const half8*)(h_t + (size_t)(l15 & 7) * HG + kbase + ko);
  f32x4 acc = {0.f, 0.f, 0.f, 0.f};
#pragma unroll 2
  for (int i = 0; i < kn; ++i) {
    float4 x = F[i * 8], y = F[i * 8 + 1];
    half8 a;
    a[0] = (_Float16)x.x; a[1] = (_Float16)x.y; a[2] = (_Float16)x.z; a[3] = (_Float16)x.w;
    a[4] = (_Float16)y.x; a[5] = (_Float16)y.y; a[6] = (_Float16)y.z; a[7] = (_Float16)y.w;
    O[i * 4] = a;                      // clamped tail rows rewrite same bytes: benign
    acc = __builtin_amdgcn_mfma_f32_16x16x32_f16(a, Bp[i * 4], acc, 0, 0, 0);
  }
  if (l15 < 8) {
    float* outp = ghp + (size_t)ks * (BB * G3) + (size_t)l15 * G3;
    int jb = blockIdx.x * 64 + wave * 16 + (lane >> 4) * 4;
#pragma unroll
    for (int r = 0; r < 4; ++r) {
      int j = jb + r;
      if (j < G3) outp[j] = acc[r];
    }
  }
}

// ---------------------------------------------------------------- gates
__global__ __launch_bounds__(256) void k_gates(const float* __restrict__ gip,
                                               const float* __restrict__ ghp,
                                               const float* __restrict__ b_ih,
                                               const float* __restrict__ b_hh,
                                               const float* __restrict__ ht_old,
                                               float* __restrict__ ht_new,
                                               _Float16* __restrict__ h_t,
                                               float* __restrict__ hout, int t) {
  int idx = blockIdx.x * 256 + threadIdx.x;
  if (idx >= BB * HG) return;
  int b = idx / HG, q = idx % HG;
  int m = t * BB + b;
  const float* g0 = gip;
  const float* g1 = gip + (size_t)MM * G3;
  float ir = b_ih[q]          + g0[m * G3 + q]          + g1[m * G3 + q];
  float iz = b_ih[q + HG]     + g0[m * G3 + q + HG]     + g1[m * G3 + q + HG];
  float in_ = b_ih[q + 2*HG]  + g0[m * G3 + q + 2*HG]   + g1[m * G3 + q + 2*HG];
  float hr = b_hh[q], hz = b_hh[q + HG], hn = b_hh[q + 2*HG];
#pragma unroll
  for (int s = 0; s < NSL; ++s) {
    const float* gh = ghp + (size_t)s * (BB * G3) + b * G3;
    hr += gh[q]; hz += gh[q + HG]; hn += gh[q + 2*HG];
  }
  float r = 1.f / (1.f + __expf(-(ir + hr)));
  float z = 1.f / (1.f + __expf(-(iz + hz)));
  float nn = tanhf(in_ + r * hn);
  float ho = ht_old[q * BB + b];
  float h = (1.f - z) * nn + z * ho;
  ht_new[q * BB + b] = h;
  h_t[(size_t)b * HG + q] = (_Float16)h;
  if (hout) hout[b * HG + q] = h;
}

// ---------------------------------------------------------------- launcher
extern "C" void kernel_launch(void* const* d_in, const int* in_sizes, int n_in,
                              void* d_out, int out_size, void* d_ws, size_t ws_size,
                              hipStream_t stream) {
  const float* x_in = (const float*)d_in[0];
  const int*   src  = (const int*)d_in[1];
  const int*   dst  = (const int*)d_in[2];
  const float* W1   = (const float*)d_in[3];
  const float* b1   = (const float*)d_in[4];
  const float* W2   = (const float*)d_in[5];
  const float* b2   = (const float*)d_in[6];
  const float* W3   = (const float*)d_in[7];
  const float* b3   = (const float*)d_in[8];
  const float* Wih  = (const float*)d_in[9];
  const float* Whh  = (const float*)d_in[10];
  const float* bih  = (const float*)d_in[11];
  const float* bhh  = (const float*)d_in[12];
  float* out = (float*)d_out;

  float* W = (float*)d_ws;
  size_t off = 0;
  float* n_out = W + off; off += 512;
  float* n_in_ = W + off; off += 512;
  float* x0    = W + off; off += (size_t)TT * NN * BB * FIN;   // 384000
  float* xa    = W + off; off += (size_t)TT * NN * BB * HH;    // 768000
  float* xb    = W + off; off += (size_t)TT * NN * BB * HH;    // 768000
  _Float16* xseq = (_Float16*)(W + off); off += (size_t)MM * IG / 2;
  float* gip   = W + off; off += (size_t)2 * MM * G3;          // 2304000
  float* ghp   = W + off; off += (size_t)NSL * BB * G3;        // 384000
  float* ht0   = W + off; off += (size_t)HG * BB;
  float* ht1   = W + off; off += (size_t)HG * BB;
  _Float16* h_t = (_Float16*)(W + off); off += (size_t)HG * BB / 2;  // [8][4000] fp16
  int* row_ptr  = (int*)(W + off); off += 512;
  int* edge_src = (int*)(W + off); off += 8000;
  off = (off + 3) & ~(size_t)3;                                // 16B align
  _Float16* whh_h = (_Float16*)(W + off); off += (size_t)G3 * HG / 2 + 64;  // 96 MB
  (void)ws_size; (void)in_sizes; (void)n_in; (void)out_size;

  k_prep_tr<<<751, 512, 0, stream>>>(src, dst, n_out, n_in_, row_ptr, edge_src, x_in, x0);
  k_gcn<FIN, HH, true, float, false><<<TT * NN, 128, 0, stream>>>(x0, W1, b1, n_out, n_in_, row_ptr, edge_src, xa);
  k_gcn<HH, HH, true, float, false><<<TT * NN, 128, 0, stream>>>(xa, W2, b2, n_out, n_in_, row_ptr, edge_src, xb);
  k_gcn<HH, HH, false, _Float16, true><<<TT * NN, 128, 0, stream>>>(xb, W3, b3, n_out, n_in_, row_ptr, edge_src, xseq);
  k_gemm_gi_mfma<<<dim3(375, 2), 256, 0, stream>>>(xseq, Wih, gip);

  // t = 0: h_old = 0 -> gh = 0, skip the W_hh stream entirely
  k_gates0<<<BB * HG / 256, 256, 0, stream>>>(gip, bih, bhh, ht0, h_t);

  float* hcur = ht0;
  float* hnxt = ht1;
  // t = 1: gh fused with the one-time fp32->fp16 W_hh conversion
  k_ghcvtm<<<dim3(188, NSL), 256, 0, stream>>>(Whh, whh_h, h_t, ghp);
  k_gates<<<(BB * HG + 255) / 256, 256, 0, stream>>>(
      gip, ghp, bih, bhh, hcur, hnxt, h_t, nullptr, 1);
  { float* tmp = hcur; hcur = hnxt; hnxt = tmp; }

  for (int t = 2; t < TT; ++t) {
    k_ghm<<<dim3(188, NSL), 256, 0, stream>>>(whh_h, h_t, ghp);
    k_gates<<<(BB * HG + 255) / 256, 256, 0, stream>>>(
        gip, ghp, bih, bhh, hcur, hnxt, h_t, (t == TT - 1) ? out : nullptr, t);
    float* tmp = hcur; hcur = hnxt; hnxt = tmp;
  }
}